// Round 7
// baseline (149.470 us; speedup 1.0000x reference)
//
#include <hip/hip_runtime.h>

#define BB 4
#define NN 16384
#define KK 16
#define DD 16
#define MTOT (BB*NN*KK)
#define NBLK 1024
#define NREP 7
#define REP_STRIDE 64            // floats: replica r, entry e at ws[r*64 + e]
#define GRP_OFF 448              // 32 group counters (unsigned), stride 16 floats (64 B)
#define ROOT_OFF 960             // root counter (unsigned)
#define WS_ZERO_BYTES (1024*4)

typedef float f32x4 __attribute__((ext_vector_type(4)));

// Gram entry enumeration over v = (c0,c1,c2, u0,u1,u2, ud)  [7 dims]:
//   e in [0,7):   S_i = sum of v_i ;  e in [7,35): G_ij (i<=j), e = 7+7i-i(i-1)/2+(j-i)
// BN mean/var per channel d derive from a_d^T G a_d (linear algebra fold);
// conv_b cancels exactly in training-mode BN.

__global__ __launch_bounds__(256, 4) void lse_fused(
    const float* __restrict__ coords,
    const float* __restrict__ features,
    const int*   __restrict__ idx,
    const float* __restrict__ dist,
    const float* __restrict__ conv_w,
    const float* __restrict__ gamma,
    const float* __restrict__ beta,
    float* __restrict__ ws,
    float* __restrict__ out)
{
    __shared__ float red[4][36];
    __shared__ float gram_s[35];
    __shared__ float sc_s[DD], b2_s[DD];
    __shared__ __align__(16) float wl[DD*8];

    const int tid = threadIdx.x;
    const int g   = blockIdx.x * 256 + tid;   // one thread per (b,n,kq): 1024*256 = 262144 quads
    const int kq  = g & 3;
    const int pos = g >> 2;
    const int n   = pos & (NN - 1);
    const int b   = pos >> 14;

    // ---------- Phase A: gather ONCE into registers ----------
    const size_t cb = (size_t)(b*NN + n) * 3;
    const float c0 = coords[cb], c1 = coords[cb+1], c2 = coords[cb+2];

    const int4   iv = *(const int4*)  (idx  + ((size_t)(b*NN + n) * KK + kq*4));
    const float4 dv = *(const float4*)(dist + ((size_t)(b*NN + n) * KK + kq*4));

    float u[4][4];   // [comp x,y,z,dist][k] — live through the write phase
    {
        int   js[4]  = {iv.x, iv.y, iv.z, iv.w};
        float ds4[4] = {dv.x, dv.y, dv.z, dv.w};
        #pragma unroll
        for (int t = 0; t < 4; ++t) {
            size_t nb = (size_t)(b*NN + js[t]) * 3;
            u[0][t] = coords[nb+0];
            u[1][t] = coords[nb+1];
            u[2][t] = coords[nb+2];
            u[3][t] = ds4[t];
        }
    }

    // Gram partials
    {
        float su[4];
        #pragma unroll
        for (int i = 0; i < 4; ++i) su[i] = (u[i][0]+u[i][1]) + (u[i][2]+u[i][3]);

        float p[35];
        p[0] = 4.f*c0; p[1] = 4.f*c1; p[2] = 4.f*c2;
        p[3] = su[0];  p[4] = su[1];  p[5] = su[2]; p[6] = su[3];
        {
            const float c[3] = {c0, c1, c2};
            #pragma unroll
            for (int i = 0; i < 7; ++i) {
                #pragma unroll
                for (int j = i; j < 7; ++j) {
                    const int e = 7 + 7*i - (i*(i-1))/2 + (j - i);
                    float v;
                    if (j < 3)       v = 4.f * c[i] * c[j];
                    else if (i < 3)  v = c[i] * su[j-3];
                    else {
                        v = 0.f;
                        #pragma unroll
                        for (int k = 0; k < 4; ++k) v = fmaf(u[i-3][k], u[j-3][k], v);
                    }
                    p[e] = v;
                }
            }
        }

        #pragma unroll
        for (int e = 0; e < 35; ++e) {
            p[e] += __shfl_xor(p[e], 1);
            p[e] += __shfl_xor(p[e], 2);
        }
        const int lane = tid & 63, wave = tid >> 6, r = lane & 3;
        float q[9];
        #pragma unroll
        for (int i = 0; i < 9; ++i) {
            float v = p[4*i];
            if (4*i+1 < 35) v = (r == 1) ? p[4*i+1] : v;
            if (4*i+2 < 35) v = (r == 2) ? p[4*i+2] : v;
            if (4*i+3 < 35) v = (r == 3) ? p[4*i+3] : v;
            q[i] = v;
        }
        #pragma unroll
        for (int i = 0; i < 9; ++i) {
            q[i] += __shfl_down(q[i], 4);
            q[i] += __shfl_down(q[i], 8);
            q[i] += __shfl_down(q[i], 16);
            q[i] += __shfl_down(q[i], 32);
        }
        if (lane < 4) {
            #pragma unroll
            for (int i = 0; i < 9; ++i) {
                int e = 4*i + lane;
                if (e < 35) red[wave][e] = q[i];
            }
        }
        __syncthreads();
        if (tid < 35) {
            float v = (red[0][tid] + red[1][tid]) + (red[2][tid] + red[3][tid]);
            atomicAdd(&ws[(blockIdx.x % NREP) * REP_STRIDE + tid], v);
        }
    }

    // ---------- Manual grid barrier (all 1024 blocks co-resident by launch_bounds) ----------
    __syncthreads();   // drains vmcnt: Gram atomics globally performed before arrival
    if (tid == 0) {
        __threadfence();
        unsigned* grp  = (unsigned*)(ws + GRP_OFF) + ((blockIdx.x >> 5) * 16);
        unsigned* root = (unsigned*)(ws + ROOT_OFF);
        unsigned old = atomicAdd(grp, 1u);
        if (old == 31u) atomicAdd(root, 1u);
        while (__hip_atomic_load(root, __ATOMIC_ACQUIRE, __HIP_MEMORY_SCOPE_AGENT) < 32u) {
            __builtin_amdgcn_s_sleep(8);
        }
    }
    __syncthreads();

    // ---------- Phase B: read Gram (agent-scope loads), finalize, stream output ----------
    if (tid < 35) {
        float s = 0.f;
        #pragma unroll
        for (int r = 0; r < NREP; ++r)
            s += __hip_atomic_load(&ws[r*REP_STRIDE + tid],
                                   __ATOMIC_RELAXED, __HIP_MEMORY_SCOPE_AGENT);
        gram_s[tid] = s;
    }
    __syncthreads();

    if (tid < DD) {
        const int d = tid;
        float a[7];
        #pragma unroll
        for (int c = 0; c < 3; ++c) {
            a[c]   = conv_w[d*10+c]   + conv_w[d*10+6+c];   // center + rel
            a[3+c] = conv_w[d*10+3+c] - conv_w[d*10+6+c];   // neighbor - rel
        }
        a[6] = conv_w[d*10+9];                              // dist
        float mean_n = 0.f, msq_n = 0.f;
        #pragma unroll
        for (int i = 0; i < 7; ++i) mean_n = fmaf(a[i], gram_s[i], mean_n);
        #pragma unroll
        for (int i = 0; i < 7; ++i) {
            #pragma unroll
            for (int j = i; j < 7; ++j) {
                const int e = 7 + 7*i - (i*(i-1))/2 + (j - i);
                const float coef = (i == j) ? 1.f : 2.f;
                msq_n = fmaf(coef * a[i] * a[j], gram_s[e], msq_n);
            }
        }
        const float inv_m = 1.0f / (float)MTOT;
        const float mean = mean_n * inv_m;
        const float var  = msq_n * inv_m - mean * mean;
        const float sc   = gamma[d] * rsqrtf(var + 1e-6f);
        sc_s[d] = sc;
        b2_s[d] = beta[d] - mean * sc;
    }
    __syncthreads();
    if (tid < 128) {
        const int d = tid >> 3, cc = tid & 7;
        float v = 0.f;
        if (cc < 3)       v = conv_w[d*10+cc] + conv_w[d*10+6+cc];
        else if (cc < 6)  v = conv_w[d*10+cc] - conv_w[d*10+cc+3];
        else if (cc == 6) v = conv_w[d*10+9];
        wl[tid] = (cc == 7) ? b2_s[d] : v * sc_s[d];
    }
    __syncthreads();

    // write phase — from registers, coalesced float4 stores (1 KB/wave/instr)
    float* op = out + ((size_t)(b*2*DD) * NN + n) * KK + kq*4;

    #pragma unroll
    for (int d = 0; d < DD; ++d) {
        float4 w0 = *(const float4*)&wl[d*8];
        float4 w1 = *(const float4*)&wl[d*8+4];
        float base = w1.w + w0.x*c0 + w0.y*c1 + w0.z*c2;   // bias folded in
        f32x4 v;
        v.x = fmaxf(base + w0.w*u[0][0] + w1.x*u[1][0] + w1.y*u[2][0] + w1.z*u[3][0], 0.f);
        v.y = fmaxf(base + w0.w*u[0][1] + w1.x*u[1][1] + w1.y*u[2][1] + w1.z*u[3][1], 0.f);
        v.z = fmaxf(base + w0.w*u[0][2] + w1.x*u[1][2] + w1.y*u[2][2] + w1.z*u[3][2], 0.f);
        v.w = fmaxf(base + w0.w*u[0][3] + w1.x*u[1][3] + w1.y*u[2][3] + w1.z*u[3][3], 0.f);
        *(f32x4*)(op + (size_t)d * NN * KK) = v;
    }

    #pragma unroll
    for (int d = 0; d < DD; ++d) {
        float f = features[(size_t)(b*DD + d) * NN + n];
        f32x4 v = {f, f, f, f};
        *(f32x4*)(op + (size_t)(DD + d) * NN * KK) = v;
    }
}

extern "C" void kernel_launch(void* const* d_in, const int* in_sizes, int n_in,
                              void* d_out, int out_size, void* d_ws, size_t ws_size,
                              hipStream_t stream)
{
    const float* coords   = (const float*)d_in[0];
    const float* features = (const float*)d_in[1];
    const int*   idx      = (const int*)  d_in[2];
    const float* dist     = (const float*)d_in[3];
    const float* conv_w   = (const float*)d_in[4];
    // d_in[5] = conv_b: cancels exactly in batch-norm, unused
    const float* gamma    = (const float*)d_in[6];
    const float* beta     = (const float*)d_in[7];
    float* ws  = (float*)d_ws;
    float* out = (float*)d_out;

    hipMemsetAsync(d_ws, 0, WS_ZERO_BYTES, stream);
    lse_fused<<<NBLK, 256, 0, stream>>>(coords, features, idx, dist,
                                        conv_w, gamma, beta, ws, out);
}

// Round 8
// 61.962 us; speedup vs baseline: 2.4123x; 2.4123x over previous
//
#include <hip/hip_runtime.h>

#define BB 4
#define NN 16384
#define KK 16
#define DD 16
#define MTOT (BB*NN*KK)
#define NBLK 1024

typedef float f32x4 __attribute__((ext_vector_type(4)));
struct __align__(4) f3 { float x, y, z; };   // 12B packed -> global_load_dwordx3

// Gram entry enumeration over v = (c0,c1,c2, u0,u1,u2, ud)  [7 dims]:
//   e in [0,7):   S_i = sum of v_i ;  e in [7,35): G_ij (i<=j), e = 7+7i-i(i-1)/2+(j-i)
// ws[0:35) = Gram totals (memset to 0, atomicAdd'ed by k1, read by k2).
// BN mean/var per channel d derive from a_d^T G a_d; conv_b cancels exactly.

// ---- k1: feature-half stream (67 MB, independent) + Gram stats hidden under it ----
__global__ __launch_bounds__(256) void lse_k1(
    const float* __restrict__ coords,
    const float* __restrict__ features,
    const int*   __restrict__ idx,
    const float* __restrict__ dist,
    float* __restrict__ ws,
    float* __restrict__ out)
{
    __shared__ float red[4][36];
    const int tid = threadIdx.x;
    const int g   = blockIdx.x * 256 + tid;   // thread per (b,n,kq)
    const int kq  = g & 3;
    const int pos = g >> 2;
    const int n   = pos & (NN - 1);
    const int b   = pos >> 14;

    // --- issue all gathers first (long latency) ---
    const f3 c = *(const f3*)(coords + (size_t)(b*NN + n) * 3);
    const int4   iv = *(const int4*)  (idx  + ((size_t)(b*NN + n) * KK + kq*4));
    const float4 dv = *(const float4*)(dist + ((size_t)(b*NN + n) * KK + kq*4));

    f3 nb[4];
    {
        int js[4] = {iv.x, iv.y, iv.z, iv.w};
        #pragma unroll
        for (int t = 0; t < 4; ++t)
            nb[t] = *(const f3*)(coords + (size_t)(b*NN + js[t]) * 3);
    }

    // --- feature-half stream while gathers are in flight ---
    {
        const float* fb  = features + (size_t)(b*DD) * NN + n;
        float* opf = out + ((size_t)(b*2*DD + DD) * NN + n) * KK + kq*4;
        #pragma unroll
        for (int d = 0; d < DD; ++d) {
            float f = fb[(size_t)d * NN];
            f32x4 v = {f, f, f, f};
            *(f32x4*)(opf + (size_t)d * NN * KK) = v;
        }
    }

    // --- Gram partials ---
    float u[4][4];
    #pragma unroll
    for (int t = 0; t < 4; ++t) { u[0][t] = nb[t].x; u[1][t] = nb[t].y; u[2][t] = nb[t].z; }
    u[3][0] = dv.x; u[3][1] = dv.y; u[3][2] = dv.z; u[3][3] = dv.w;

    float su[4];
    #pragma unroll
    for (int i = 0; i < 4; ++i) su[i] = (u[i][0]+u[i][1]) + (u[i][2]+u[i][3]);

    float p[35];
    p[0] = 4.f*c.x; p[1] = 4.f*c.y; p[2] = 4.f*c.z;
    p[3] = su[0];   p[4] = su[1];   p[5] = su[2]; p[6] = su[3];
    {
        const float cc[3] = {c.x, c.y, c.z};
        #pragma unroll
        for (int i = 0; i < 7; ++i) {
            #pragma unroll
            for (int j = i; j < 7; ++j) {
                const int e = 7 + 7*i - (i*(i-1))/2 + (j - i);
                float v;
                if (j < 3)       v = 4.f * cc[i] * cc[j];
                else if (i < 3)  v = cc[i] * su[j-3];
                else {
                    v = 0.f;
                    #pragma unroll
                    for (int k = 0; k < 4; ++k) v = fmaf(u[i-3][k], u[j-3][k], v);
                }
                p[e] = v;
            }
        }
    }

    #pragma unroll
    for (int e = 0; e < 35; ++e) {
        p[e] += __shfl_xor(p[e], 1);
        p[e] += __shfl_xor(p[e], 2);
    }
    const int lane = tid & 63, wave = tid >> 6, r = lane & 3;
    float q[9];
    #pragma unroll
    for (int i = 0; i < 9; ++i) {
        float v = p[4*i];
        if (4*i+1 < 35) v = (r == 1) ? p[4*i+1] : v;
        if (4*i+2 < 35) v = (r == 2) ? p[4*i+2] : v;
        if (4*i+3 < 35) v = (r == 3) ? p[4*i+3] : v;
        q[i] = v;
    }
    #pragma unroll
    for (int i = 0; i < 9; ++i) {
        q[i] += __shfl_down(q[i], 4);
        q[i] += __shfl_down(q[i], 8);
        q[i] += __shfl_down(q[i], 16);
        q[i] += __shfl_down(q[i], 32);
    }
    if (lane < 4) {
        #pragma unroll
        for (int i = 0; i < 9; ++i) {
            int e = 4*i + lane;
            if (e < 35) red[wave][e] = q[i];
        }
    }
    __syncthreads();
    if (tid < 35) {
        float v = (red[0][tid] + red[1][tid]) + (red[2][tid] + red[3][tid]);
        atomicAdd(&ws[tid], v);
    }
}

// ---- k2: BN-half stream (67 MB) with inline per-block finalize prefix ----
__global__ __launch_bounds__(256) void lse_k2(
    const float* __restrict__ coords,
    const int*   __restrict__ idx,
    const float* __restrict__ dist,
    const float* __restrict__ conv_w,
    const float* __restrict__ gamma,
    const float* __restrict__ beta,
    const float* __restrict__ ws,
    float* __restrict__ out)
{
    __shared__ float gram_s[35];
    __shared__ float sc_s[DD], b2_s[DD];
    __shared__ __align__(16) float wl[DD*8];
    const int tid = threadIdx.x;

    if (tid < 35) gram_s[tid] = ws[tid];
    __syncthreads();

    if (tid < DD) {                       // ~60 FMA, redundant per block
        const int d = tid;
        float a[7];
        #pragma unroll
        for (int c = 0; c < 3; ++c) {
            a[c]   = conv_w[d*10+c]   + conv_w[d*10+6+c];   // center + rel
            a[3+c] = conv_w[d*10+3+c] - conv_w[d*10+6+c];   // neighbor - rel
        }
        a[6] = conv_w[d*10+9];                              // dist
        float mean_n = 0.f, msq_n = 0.f;
        #pragma unroll
        for (int i = 0; i < 7; ++i) mean_n = fmaf(a[i], gram_s[i], mean_n);
        #pragma unroll
        for (int i = 0; i < 7; ++i) {
            #pragma unroll
            for (int j = i; j < 7; ++j) {
                const int e = 7 + 7*i - (i*(i-1))/2 + (j - i);
                const float coef = (i == j) ? 1.f : 2.f;
                msq_n = fmaf(coef * a[i] * a[j], gram_s[e], msq_n);
            }
        }
        const float inv_m = 1.0f / (float)MTOT;
        const float mean = mean_n * inv_m;
        const float var  = msq_n * inv_m - mean * mean;
        const float sc   = gamma[d] * rsqrtf(var + 1e-6f);
        sc_s[d] = sc;
        b2_s[d] = beta[d] - mean * sc;
    }
    __syncthreads();
    if (tid < 128) {
        const int d = tid >> 3, cc = tid & 7;
        float v = 0.f;
        if (cc < 3)       v = conv_w[d*10+cc] + conv_w[d*10+6+cc];
        else if (cc < 6)  v = conv_w[d*10+cc] - conv_w[d*10+cc+3];
        else if (cc == 6) v = conv_w[d*10+9];
        wl[tid] = (cc == 7) ? b2_s[d] : v * sc_s[d];
    }
    __syncthreads();

    const int g   = blockIdx.x * 256 + tid;  // thread per (b,n,kq)
    const int kq  = g & 3;
    const int pos = g >> 2;
    const int n   = pos & (NN - 1);
    const int b   = pos >> 14;

    const f3 c = *(const f3*)(coords + (size_t)(b*NN + n) * 3);
    const int4   iv = *(const int4*)  (idx  + ((size_t)(b*NN + n) * KK + kq*4));
    const float4 dv = *(const float4*)(dist + ((size_t)(b*NN + n) * KK + kq*4));

    f3 nb[4];
    {
        int js[4] = {iv.x, iv.y, iv.z, iv.w};
        #pragma unroll
        for (int t = 0; t < 4; ++t)
            nb[t] = *(const f3*)(coords + (size_t)(b*NN + js[t]) * 3);
    }
    float ux[4], uy[4], uz[4], ud[4];
    #pragma unroll
    for (int t = 0; t < 4; ++t) { ux[t] = nb[t].x; uy[t] = nb[t].y; uz[t] = nb[t].z; }
    ud[0] = dv.x; ud[1] = dv.y; ud[2] = dv.z; ud[3] = dv.w;

    float* op = out + ((size_t)(b*2*DD) * NN + n) * KK + kq*4;

    #pragma unroll
    for (int d = 0; d < DD; ++d) {
        float4 w0 = *(const float4*)&wl[d*8];
        float4 w1 = *(const float4*)&wl[d*8+4];
        float base = w1.w + w0.x*c.x + w0.y*c.y + w0.z*c.z;   // bias folded in
        f32x4 v;
        v.x = fmaxf(base + w0.w*ux[0] + w1.x*uy[0] + w1.y*uz[0] + w1.z*ud[0], 0.f);
        v.y = fmaxf(base + w0.w*ux[1] + w1.x*uy[1] + w1.y*uz[1] + w1.z*ud[1], 0.f);
        v.z = fmaxf(base + w0.w*ux[2] + w1.x*uy[2] + w1.y*uz[2] + w1.z*ud[2], 0.f);
        v.w = fmaxf(base + w0.w*ux[3] + w1.x*uy[3] + w1.y*uz[3] + w1.z*ud[3], 0.f);
        *(f32x4*)(op + (size_t)d * NN * KK) = v;
    }
}

extern "C" void kernel_launch(void* const* d_in, const int* in_sizes, int n_in,
                              void* d_out, int out_size, void* d_ws, size_t ws_size,
                              hipStream_t stream)
{
    const float* coords   = (const float*)d_in[0];
    const float* features = (const float*)d_in[1];
    const int*   idx      = (const int*)  d_in[2];
    const float* dist     = (const float*)d_in[3];
    const float* conv_w   = (const float*)d_in[4];
    // d_in[5] = conv_b: cancels exactly in batch-norm, unused
    const float* gamma    = (const float*)d_in[6];
    const float* beta     = (const float*)d_in[7];
    float* ws  = (float*)d_ws;
    float* out = (float*)d_out;

    hipMemsetAsync(d_ws, 0, 35 * sizeof(float), stream);
    lse_k1<<<NBLK, 256, 0, stream>>>(coords, features, idx, dist, ws, out);
    lse_k2<<<NBLK, 256, 0, stream>>>(coords, idx, dist, conv_w, gamma, beta, ws, out);
}

// Round 9
// 54.193 us; speedup vs baseline: 2.7581x; 1.1434x over previous
//
#include <hip/hip_runtime.h>

#define BB 4
#define NN 16384
#define KK 16
#define DD 16
#define MTOT (BB*NN*KK)
#define NBLK 1024
#define NREP 8
#define REP_STRIDE 64    // floats between replica sets (256 B -> distinct line pairs)

typedef float f32x4 __attribute__((ext_vector_type(4)));
struct __align__(4) f3 { float x, y, z; };   // 12B packed -> global_load_dwordx3

// Gram entry enumeration over v = (c0,c1,c2, u0,u1,u2, ud)  [7 dims]:
//   e in [0,7):   S_i = sum of v_i ;  e in [7,35): G_ij (i<=j), e = 7+7i-i(i-1)/2+(j-i)
// ws[r*64 + e], r=0..7: replicated Gram accumulators (memset to 0; block r=blk&7).
// BN mean/var per channel d derive from a_d^T G a_d; conv_b cancels exactly.

// ---- k1: feature-half stream (67 MB, independent) + Gram stats hidden under it ----
__global__ __launch_bounds__(256) void lse_k1(
    const float* __restrict__ coords,
    const float* __restrict__ features,
    const int*   __restrict__ idx,
    const float* __restrict__ dist,
    float* __restrict__ ws,
    float* __restrict__ out)
{
    __shared__ float red[4][36];
    const int tid = threadIdx.x;
    const int g   = blockIdx.x * 256 + tid;   // thread per (b,n,kq)
    const int kq  = g & 3;
    const int pos = g >> 2;
    const int n   = pos & (NN - 1);
    const int b   = pos >> 14;

    // --- issue all gathers first (long latency) ---
    const f3 c = *(const f3*)(coords + (size_t)(b*NN + n) * 3);
    const int4   iv = *(const int4*)  (idx  + ((size_t)(b*NN + n) * KK + kq*4));
    const float4 dv = *(const float4*)(dist + ((size_t)(b*NN + n) * KK + kq*4));

    f3 nb[4];
    {
        int js[4] = {iv.x, iv.y, iv.z, iv.w};
        #pragma unroll
        for (int t = 0; t < 4; ++t)
            nb[t] = *(const f3*)(coords + (size_t)(b*NN + js[t]) * 3);
    }

    // --- feature-half stream while gathers are in flight ---
    {
        const float* fb  = features + (size_t)(b*DD) * NN + n;
        float* opf = out + ((size_t)(b*2*DD + DD) * NN + n) * KK + kq*4;
        #pragma unroll
        for (int d = 0; d < DD; ++d) {
            float f = fb[(size_t)d * NN];
            f32x4 v = {f, f, f, f};
            *(f32x4*)(opf + (size_t)d * NN * KK) = v;
        }
    }

    // --- Gram partials ---
    float u[4][4];
    #pragma unroll
    for (int t = 0; t < 4; ++t) { u[0][t] = nb[t].x; u[1][t] = nb[t].y; u[2][t] = nb[t].z; }
    u[3][0] = dv.x; u[3][1] = dv.y; u[3][2] = dv.z; u[3][3] = dv.w;

    float su[4];
    #pragma unroll
    for (int i = 0; i < 4; ++i) su[i] = (u[i][0]+u[i][1]) + (u[i][2]+u[i][3]);

    float p[35];
    p[0] = 4.f*c.x; p[1] = 4.f*c.y; p[2] = 4.f*c.z;
    p[3] = su[0];   p[4] = su[1];   p[5] = su[2]; p[6] = su[3];
    {
        const float cc[3] = {c.x, c.y, c.z};
        #pragma unroll
        for (int i = 0; i < 7; ++i) {
            #pragma unroll
            for (int j = i; j < 7; ++j) {
                const int e = 7 + 7*i - (i*(i-1))/2 + (j - i);
                float v;
                if (j < 3)       v = 4.f * cc[i] * cc[j];
                else if (i < 3)  v = cc[i] * su[j-3];
                else {
                    v = 0.f;
                    #pragma unroll
                    for (int k = 0; k < 4; ++k) v = fmaf(u[i-3][k], u[j-3][k], v);
                }
                p[e] = v;
            }
        }
    }

    #pragma unroll
    for (int e = 0; e < 35; ++e) {
        p[e] += __shfl_xor(p[e], 1);
        p[e] += __shfl_xor(p[e], 2);
    }
    const int lane = tid & 63, wave = tid >> 6, r = lane & 3;
    float q[9];
    #pragma unroll
    for (int i = 0; i < 9; ++i) {
        float v = p[4*i];
        if (4*i+1 < 35) v = (r == 1) ? p[4*i+1] : v;
        if (4*i+2 < 35) v = (r == 2) ? p[4*i+2] : v;
        if (4*i+3 < 35) v = (r == 3) ? p[4*i+3] : v;
        q[i] = v;
    }
    #pragma unroll
    for (int i = 0; i < 9; ++i) {
        q[i] += __shfl_down(q[i], 4);
        q[i] += __shfl_down(q[i], 8);
        q[i] += __shfl_down(q[i], 16);
        q[i] += __shfl_down(q[i], 32);
    }
    if (lane < 4) {
        #pragma unroll
        for (int i = 0; i < 9; ++i) {
            int e = 4*i + lane;
            if (e < 35) red[wave][e] = q[i];
        }
    }
    __syncthreads();
    if (tid < 35) {
        float v = (red[0][tid] + red[1][tid]) + (red[2][tid] + red[3][tid]);
        atomicAdd(&ws[(blockIdx.x & (NREP-1)) * REP_STRIDE + tid], v);
    }
}

// ---- k2: BN-half stream (67 MB) with inline per-block finalize prefix ----
__global__ __launch_bounds__(256) void lse_k2(
    const float* __restrict__ coords,
    const int*   __restrict__ idx,
    const float* __restrict__ dist,
    const float* __restrict__ conv_w,
    const float* __restrict__ gamma,
    const float* __restrict__ beta,
    const float* __restrict__ ws,
    float* __restrict__ out)
{
    __shared__ float gram_s[35];
    __shared__ float sc_s[DD], b2_s[DD];
    __shared__ __align__(16) float wl[DD*8];
    const int tid = threadIdx.x;

    if (tid < 35) {
        float s = 0.f;
        #pragma unroll
        for (int r = 0; r < NREP; ++r) s += ws[r*REP_STRIDE + tid];
        gram_s[tid] = s;
    }
    __syncthreads();

    if (tid < DD) {                       // ~60 FMA, redundant per block
        const int d = tid;
        float a[7];
        #pragma unroll
        for (int c = 0; c < 3; ++c) {
            a[c]   = conv_w[d*10+c]   + conv_w[d*10+6+c];   // center + rel
            a[3+c] = conv_w[d*10+3+c] - conv_w[d*10+6+c];   // neighbor - rel
        }
        a[6] = conv_w[d*10+9];                              // dist
        float mean_n = 0.f, msq_n = 0.f;
        #pragma unroll
        for (int i = 0; i < 7; ++i) mean_n = fmaf(a[i], gram_s[i], mean_n);
        #pragma unroll
        for (int i = 0; i < 7; ++i) {
            #pragma unroll
            for (int j = i; j < 7; ++j) {
                const int e = 7 + 7*i - (i*(i-1))/2 + (j - i);
                const float coef = (i == j) ? 1.f : 2.f;
                msq_n = fmaf(coef * a[i] * a[j], gram_s[e], msq_n);
            }
        }
        const float inv_m = 1.0f / (float)MTOT;
        const float mean = mean_n * inv_m;
        const float var  = msq_n * inv_m - mean * mean;
        const float sc   = gamma[d] * rsqrtf(var + 1e-6f);
        sc_s[d] = sc;
        b2_s[d] = beta[d] - mean * sc;
    }
    __syncthreads();
    if (tid < 128) {
        const int d = tid >> 3, cc = tid & 7;
        float v = 0.f;
        if (cc < 3)       v = conv_w[d*10+cc] + conv_w[d*10+6+cc];
        else if (cc < 6)  v = conv_w[d*10+cc] - conv_w[d*10+cc+3];
        else if (cc == 6) v = conv_w[d*10+9];
        wl[tid] = (cc == 7) ? b2_s[d] : v * sc_s[d];
    }
    __syncthreads();

    const int g   = blockIdx.x * 256 + tid;  // thread per (b,n,kq)
    const int kq  = g & 3;
    const int pos = g >> 2;
    const int n   = pos & (NN - 1);
    const int b   = pos >> 14;

    const f3 c = *(const f3*)(coords + (size_t)(b*NN + n) * 3);
    const int4   iv = *(const int4*)  (idx  + ((size_t)(b*NN + n) * KK + kq*4));
    const float4 dv = *(const float4*)(dist + ((size_t)(b*NN + n) * KK + kq*4));

    f3 nb[4];
    {
        int js[4] = {iv.x, iv.y, iv.z, iv.w};
        #pragma unroll
        for (int t = 0; t < 4; ++t)
            nb[t] = *(const f3*)(coords + (size_t)(b*NN + js[t]) * 3);
    }
    float ux[4], uy[4], uz[4], ud[4];
    #pragma unroll
    for (int t = 0; t < 4; ++t) { ux[t] = nb[t].x; uy[t] = nb[t].y; uz[t] = nb[t].z; }
    ud[0] = dv.x; ud[1] = dv.y; ud[2] = dv.z; ud[3] = dv.w;

    float* op = out + ((size_t)(b*2*DD) * NN + n) * KK + kq*4;

    #pragma unroll
    for (int d = 0; d < DD; ++d) {
        float4 w0 = *(const float4*)&wl[d*8];
        float4 w1 = *(const float4*)&wl[d*8+4];
        float base = w1.w + w0.x*c.x + w0.y*c.y + w0.z*c.z;   // bias folded in
        f32x4 v;
        v.x = fmaxf(base + w0.w*ux[0] + w1.x*uy[0] + w1.y*uz[0] + w1.z*ud[0], 0.f);
        v.y = fmaxf(base + w0.w*ux[1] + w1.x*uy[1] + w1.y*uz[1] + w1.z*ud[1], 0.f);
        v.z = fmaxf(base + w0.w*ux[2] + w1.x*uy[2] + w1.y*uz[2] + w1.z*ud[2], 0.f);
        v.w = fmaxf(base + w0.w*ux[3] + w1.x*uy[3] + w1.y*uz[3] + w1.z*ud[3], 0.f);
        *(f32x4*)(op + (size_t)d * NN * KK) = v;
    }
}

extern "C" void kernel_launch(void* const* d_in, const int* in_sizes, int n_in,
                              void* d_out, int out_size, void* d_ws, size_t ws_size,
                              hipStream_t stream)
{
    const float* coords   = (const float*)d_in[0];
    const float* features = (const float*)d_in[1];
    const int*   idx      = (const int*)  d_in[2];
    const float* dist     = (const float*)d_in[3];
    const float* conv_w   = (const float*)d_in[4];
    // d_in[5] = conv_b: cancels exactly in batch-norm, unused
    const float* gamma    = (const float*)d_in[6];
    const float* beta     = (const float*)d_in[7];
    float* ws  = (float*)d_ws;
    float* out = (float*)d_out;

    hipMemsetAsync(d_ws, 0, NREP * REP_STRIDE * sizeof(float), stream);
    lse_k1<<<NBLK, 256, 0, stream>>>(coords, features, idx, dist, ws, out);
    lse_k2<<<NBLK, 256, 0, stream>>>(coords, idx, dist, conv_w, gamma, beta, ws, out);
}